// Round 2
// baseline (1855.124 us; speedup 1.0000x reference)
//
#include <hip/hip_runtime.h>
#include <hip/hip_bf16.h>
#include <cstdint>

typedef __bf16 bf16;
typedef __attribute__((ext_vector_type(4))) __bf16 bf16x4;
typedef __attribute__((ext_vector_type(8))) __bf16 bf16x8;
typedef __attribute__((ext_vector_type(4))) float f32x4;

#define AS1 __attribute__((address_space(1)))
#define AS3 __attribute__((address_space(3)))

__device__ __forceinline__ unsigned short f2bf(float x) {
    union { __bf16 b; unsigned short u; } c;
    c.b = (__bf16)x;
    return c.u;
}

// async global->LDS, 16B per lane. LDS dest = wave-uniform base + lane*16.
__device__ __forceinline__ void gld_lds16(const void* g, void* lds_wave_base) {
#if __has_builtin(__builtin_amdgcn_global_load_lds)
    __builtin_amdgcn_global_load_lds((AS1 void*)(uintptr_t)g,
                                     (AS3 void*)(uint32_t)(uintptr_t)lds_wave_base,
                                     16u, 0, 0u);
#else
    int lane = threadIdx.x & 63;
    *(uint4*)((char*)lds_wave_base + lane * 16) = *(const uint4*)g;
#endif
}

// ---------------- fp32 -> bf16 elementwise (n multiple of 1024) ----------------
__global__ __launch_bounds__(256) void cvt_kernel(const float* __restrict__ in,
                                                  bf16* __restrict__ out) {
    int i = (blockIdx.x * 256 + threadIdx.x) * 4;
    float4 v = *(const float4*)&in[i];
    bf16x4 o;
    o[0] = (__bf16)v.x; o[1] = (__bf16)v.y; o[2] = (__bf16)v.z; o[3] = (__bf16)v.w;
    *(bf16x4*)&out[i] = o;
}

// ---------------- fp32 [k][n] -> bf16 out[n][k] transpose+convert, n = 4096 ----------------
__global__ __launch_bounds__(256) void cvt_transpose_kernel(const float* __restrict__ in,
                                                            unsigned short* __restrict__ out, int n) {
    __shared__ unsigned short tile[64][65];
    int t = threadIdx.x;
    int n0 = blockIdx.x * 64, k0 = blockIdx.y * 64;
#pragma unroll
    for (int i = 0; i < 4; i++) {
        int idx = t + i * 256;
        int r = idx >> 4, cc = (idx & 15) * 4;
        float4 v = *(const float4*)&in[(size_t)(k0 + r) * n + n0 + cc];
        tile[r][cc + 0] = f2bf(v.x); tile[r][cc + 1] = f2bf(v.y);
        tile[r][cc + 2] = f2bf(v.z); tile[r][cc + 3] = f2bf(v.w);
    }
    __syncthreads();
#pragma unroll
    for (int i = 0; i < 4; i++) {
        int idx = t + i * 256;
        int nn = idx >> 4, kc = (idx & 15) * 4;
        ushort4 v;
        v.x = tile[kc + 0][nn]; v.y = tile[kc + 1][nn];
        v.z = tile[kc + 2][nn]; v.w = tile[kc + 3][nn];
        *(ushort4*)&out[(size_t)(n0 + nn) * n + k0 + kc] = v;
    }
}

// ---------------- GEMM: C[m,n] = sum_k A[m,k]*BT[n,k] + bias[n] (+ resid) ----------------
// m97 structure: 128x128 tile, BK=32, 256 thr = 4 waves (2x2 of 64x64), 16x16x32 bf16 MFMA.
// MODE 0: write bf16 C, no residual. MODE 1: write fp32 C, add bf16 residual.
template <int MODE>
__global__ __launch_bounds__(256) void gemm_bt_kernel(
    const bf16* __restrict__ A, const bf16* __restrict__ BT,
    const float* __restrict__ bias, const bf16* __restrict__ resid,
    void* __restrict__ Cout, int M, int N, int K) {
    __shared__ __align__(16) bf16 As[128 * 32];
    __shared__ __align__(16) bf16 Bs[128 * 32];
    const int tid = threadIdx.x;
    const int wave = tid >> 6, lane = tid & 63;
    const int row0 = blockIdx.x * 128, col0 = blockIdx.y * 128;
    const int wr = wave >> 1, wc = wave & 1;
    const int lq = lane >> 4, lm = lane & 15;

    f32x4 acc[4][4];
#pragma unroll
    for (int mt = 0; mt < 4; mt++)
#pragma unroll
        for (int nt = 0; nt < 4; nt++) acc[mt][nt] = (f32x4){0.f, 0.f, 0.f, 0.f};

    const bf16* Ab = A + (size_t)row0 * K;
    const bf16* Bb = BT + (size_t)col0 * K;

    for (int k0 = 0; k0 < K; k0 += 32) {
#pragma unroll
        for (int i = 0; i < 2; i++) {
            int t = wave * 2 + i;             // issue id 0..7 (wave-uniform)
            int c = t * 64 + lane;            // chunk id 0..511
            int r = c >> 2, kc = c & 3;       // r: tile row, kc: 8-elem K chunk
            gld_lds16(Ab + (size_t)r * K + k0 + kc * 8, &As[t * 512]);
            gld_lds16(Bb + (size_t)r * K + k0 + kc * 8, &Bs[t * 512]);
        }
        __syncthreads();   // compiler emits vmcnt(0) drain before barrier
        bf16x8 af[4], bfr[4];
#pragma unroll
        for (int mt = 0; mt < 4; mt++) {
            int r = wr * 64 + mt * 16 + lm;
            af[mt] = *(const bf16x8*)&As[r * 32 + lq * 8];
        }
#pragma unroll
        for (int nt = 0; nt < 4; nt++) {
            int r = wc * 64 + nt * 16 + lm;
            bfr[nt] = *(const bf16x8*)&Bs[r * 32 + lq * 8];
        }
#pragma unroll
        for (int mt = 0; mt < 4; mt++)
#pragma unroll
            for (int nt = 0; nt < 4; nt++)
                acc[mt][nt] = __builtin_amdgcn_mfma_f32_16x16x32_bf16(af[mt], bfr[nt], acc[mt][nt], 0, 0, 0);
        __syncthreads();
    }

    // C/D layout (m89/m91-verified): col = lane&15, row = (lane>>4)*4 + reg
#pragma unroll
    for (int nt = 0; nt < 4; nt++) {
        int col = col0 + wc * 64 + nt * 16 + lm;
        float bv = bias[col];
#pragma unroll
        for (int mt = 0; mt < 4; mt++) {
            int rbase = row0 + wr * 64 + mt * 16 + lq * 4;
#pragma unroll
            for (int r = 0; r < 4; r++) {
                int row = rbase + r;
                float v = acc[mt][nt][r] + bv;
                if (MODE == 0) {
                    ((bf16*)Cout)[(size_t)row * N + col] = (bf16)v;
                } else {
                    v += (float)resid[(size_t)row * N + col];
                    ((float*)Cout)[(size_t)row * N + col] = v;
                }
            }
        }
    }
}

// ---------------- block-diagonal attention + residual ----------------
// grid: (nseg*8, 36). block handles (seg, head, 32-row i-tile). Writes res1 = ctx + X into R1 (bf16).
__global__ __launch_bounds__(256) void attn_kernel(
    const bf16* __restrict__ Q, const bf16* __restrict__ K, const bf16* __restrict__ V,
    const int* __restrict__ num_rels, const float* __restrict__ X,
    bf16* __restrict__ R1, int nseg) {
    const float SCALE = 0.044194173824159216f;  // 1/sqrt(512)
    int seg = blockIdx.x >> 3;
    int h = blockIdx.x & 7;
    int S = 0;
    for (int i = 0; i < seg; i++) S += num_rels[i];
    int L = num_rels[seg];
    int i0 = blockIdx.y * 32;
    if (i0 >= L) return;
    int icount = min(32, L - i0);

    __shared__ __align__(16) bf16 Qs[32][512];
    __shared__ __align__(16) bf16 KVs[32][512];   // K then V, sequentially
    __shared__ float Sx[32][33];
    __shared__ float mrow[32], lrow[32], arow[32];

    int t = threadIdx.x;
    int row = t >> 3;           // 0..31: score row / output row
    int c0 = (t & 7) * 64;      // output column block within head
    int jb = (t & 7) * 4;       // 4 score columns

#pragma unroll
    for (int it = 0; it < 8; it++) {
        int c = t + it * 256;
        int r = c >> 6, cc = (c & 63) * 8;
        uint4 val = make_uint4(0u, 0u, 0u, 0u);
        if (r < icount) val = *(const uint4*)&Q[(size_t)(S + i0 + r) * 4096 + h * 512 + cc];
        *(uint4*)&Qs[r][cc] = val;
    }
    if (t < 32) { mrow[t] = -1e30f; lrow[t] = 0.f; }
    float o[64];
#pragma unroll
    for (int c = 0; c < 64; c++) o[c] = 0.f;
    __syncthreads();

    for (int j0 = 0; j0 < L; j0 += 32) {
        int jcount = min(32, L - j0);
        // K tile
#pragma unroll
        for (int it = 0; it < 8; it++) {
            int c = t + it * 256;
            int r = c >> 6, cc = (c & 63) * 8;
            uint4 val = make_uint4(0u, 0u, 0u, 0u);
            if (r < jcount) val = *(const uint4*)&K[(size_t)(S + j0 + r) * 4096 + h * 512 + cc];
            *(uint4*)&KVs[r][cc] = val;
        }
        __syncthreads();
        // scores: thread (row, jb..jb+3)
        float s[4] = {0.f, 0.f, 0.f, 0.f};
        for (int d = 0; d < 512; d += 8) {
            bf16x8 qv = *(const bf16x8*)&Qs[row][d];
            float qf[8];
#pragma unroll
            for (int e = 0; e < 8; e++) qf[e] = (float)qv[e];
#pragma unroll
            for (int jj = 0; jj < 4; jj++) {
                bf16x8 kv = *(const bf16x8*)&KVs[jb + jj][d];
#pragma unroll
                for (int e = 0; e < 8; e++) s[jj] += qf[e] * (float)kv[e];
            }
        }
#pragma unroll
        for (int jj = 0; jj < 4; jj++) Sx[row][jb + jj] = s[jj] * SCALE;
        __syncthreads();
        // online softmax update (one thread per row)
        if (t < 32) {
            float m_old = mrow[t];
            float mx = m_old;
            for (int j = 0; j < jcount; j++) mx = fmaxf(mx, Sx[t][j]);
            float alpha = __expf(m_old - mx);
            float sum = 0.f;
            for (int j = 0; j < jcount; j++) {
                float p = __expf(Sx[t][j] - mx);
                Sx[t][j] = p;
                sum += p;
            }
            lrow[t] = lrow[t] * alpha + sum;
            mrow[t] = mx;
            arow[t] = alpha;
        }
        __syncthreads();
        // V tile (overwrites K tile)
#pragma unroll
        for (int it = 0; it < 8; it++) {
            int c = t + it * 256;
            int r = c >> 6, cc = (c & 63) * 8;
            uint4 val = make_uint4(0u, 0u, 0u, 0u);
            if (r < jcount) val = *(const uint4*)&V[(size_t)(S + j0 + r) * 4096 + h * 512 + cc];
            *(uint4*)&KVs[r][cc] = val;
        }
        __syncthreads();
        // rescale + accumulate PV: thread (row, c0..c0+63)
        float alpha = arow[row];
#pragma unroll
        for (int c = 0; c < 64; c++) o[c] *= alpha;
        for (int j = 0; j < jcount; j++) {
            float p = Sx[row][j];
#pragma unroll
            for (int c = 0; c < 64; c += 8) {
                bf16x8 vv = *(const bf16x8*)&KVs[j][c0 + c];
#pragma unroll
                for (int e = 0; e < 8; e++) o[c + e] += p * (float)vv[e];
            }
        }
        __syncthreads();
    }

    if (row < icount) {
        float inv = 1.f / lrow[row];
        size_t base = (size_t)(S + i0 + row) * 4096 + h * 512 + c0;
#pragma unroll
        for (int c = 0; c < 64; c++) {
            float v = o[c] * inv + X[base + c];
            R1[base + c] = (bf16)v;
        }
    }
}

extern "C" void kernel_launch(void* const* d_in, const int* in_sizes, int n_in,
                              void* d_out, int out_size, void* d_ws, size_t ws_size,
                              hipStream_t stream) {
    const float* prod = (const float*)d_in[0];
    const int* nr = (const int*)d_in[1];
    const float* Wq = (const float*)d_in[2];
    const float* bq = (const float*)d_in[3];
    const float* Wk = (const float*)d_in[4];
    const float* bk = (const float*)d_in[5];
    const float* Wv = (const float*)d_in[6];
    const float* bv = (const float*)d_in[7];
    const float* Wfc = (const float*)d_in[8];
    const float* bfc = (const float*)d_in[9];
    float* out = (float*)d_out;

    const size_t MATB = (size_t)4096 * 4096 * sizeof(bf16);  // 33.55 MB
    char* ws = (char*)d_ws;
    bf16* Xb = (bf16*)(ws + 0 * MATB);   // bf16 prod_rep
    bf16* Qb = (bf16*)(ws + 1 * MATB);   // later reused as res1
    bf16* Kb = (bf16*)(ws + 2 * MATB);
    bf16* Vb = (bf16*)(ws + 3 * MATB);
    bf16* WT = (bf16*)(ws + 4 * MATB);   // reused for each weight transpose

    int nseg = in_sizes[1];

    dim3 cb(256), cg(16384);             // 4096*4096/1024
    dim3 tb(256), tg(64, 64);
    dim3 gb(256), gg(32, 32);

    cvt_kernel<<<cg, cb, 0, stream>>>(prod, Xb);

    cvt_transpose_kernel<<<tg, tb, 0, stream>>>(Wq, (unsigned short*)WT, 4096);
    gemm_bt_kernel<0><<<gg, gb, 0, stream>>>(Xb, WT, bq, nullptr, Qb, 4096, 4096, 4096);
    cvt_transpose_kernel<<<tg, tb, 0, stream>>>(Wk, (unsigned short*)WT, 4096);
    gemm_bt_kernel<0><<<gg, gb, 0, stream>>>(Xb, WT, bk, nullptr, Kb, 4096, 4096, 4096);
    cvt_transpose_kernel<<<tg, tb, 0, stream>>>(Wv, (unsigned short*)WT, 4096);
    gemm_bt_kernel<0><<<gg, gb, 0, stream>>>(Xb, WT, bv, nullptr, Vb, 4096, 4096, 4096);

    dim3 ab(256), ag(nseg * 8, 36);  // 36 tiles covers Lmax <= 1152 > 1120 bound
    attn_kernel<<<ag, ab, 0, stream>>>(Qb, Kb, Vb, nr, prod, Qb, nseg);

    cvt_transpose_kernel<<<tg, tb, 0, stream>>>(Wfc, (unsigned short*)WT, 4096);
    gemm_bt_kernel<1><<<gg, gb, 0, stream>>>(Qb, WT, bfc, Qb, out, 4096, 4096, 4096);
}

// Round 3
// 1246.893 us; speedup vs baseline: 1.4878x; 1.4878x over previous
//
#include <hip/hip_runtime.h>
#include <hip/hip_bf16.h>
#include <cstdint>

typedef __bf16 bf16;
typedef __attribute__((ext_vector_type(4))) __bf16 bf16x4;
typedef __attribute__((ext_vector_type(8))) __bf16 bf16x8;
typedef __attribute__((ext_vector_type(4))) float f32x4;

#define AS1 __attribute__((address_space(1)))
#define AS3 __attribute__((address_space(3)))

__device__ __forceinline__ unsigned short f2bf(float x) {
    union { __bf16 b; unsigned short u; } c;
    c.b = (__bf16)x;
    return c.u;
}

// async global->LDS, 16B per lane. LDS dest = wave-uniform base + lane*16.
__device__ __forceinline__ void gld_lds16(const void* g, void* lds_wave_base) {
#if __has_builtin(__builtin_amdgcn_global_load_lds)
    __builtin_amdgcn_global_load_lds((AS1 void*)(uintptr_t)g,
                                     (AS3 void*)(uint32_t)(uintptr_t)lds_wave_base,
                                     16u, 0, 0u);
#else
    int lane = threadIdx.x & 63;
    *(uint4*)((char*)lds_wave_base + lane * 16) = *(const uint4*)g;
#endif
}

// ---------------- fp32 -> bf16 elementwise ----------------
__global__ __launch_bounds__(256) void cvt_kernel(const float* __restrict__ in,
                                                  bf16* __restrict__ out) {
    int i = (blockIdx.x * 256 + threadIdx.x) * 4;
    float4 v = *(const float4*)&in[i];
    bf16x4 o;
    o[0] = (__bf16)v.x; o[1] = (__bf16)v.y; o[2] = (__bf16)v.z; o[3] = (__bf16)v.w;
    *(bf16x4*)&out[i] = o;
}

// ---------------- fp32 [k][n] -> bf16 out[n][k] transpose+convert, n = 4096 ----------------
__global__ __launch_bounds__(256) void cvt_transpose_kernel(const float* __restrict__ in,
                                                            unsigned short* __restrict__ out, int n) {
    __shared__ unsigned short tile[64][65];
    int t = threadIdx.x;
    int n0 = blockIdx.x * 64, k0 = blockIdx.y * 64;
#pragma unroll
    for (int i = 0; i < 4; i++) {
        int idx = t + i * 256;
        int r = idx >> 4, cc = (idx & 15) * 4;
        float4 v = *(const float4*)&in[(size_t)(k0 + r) * n + n0 + cc];
        tile[r][cc + 0] = f2bf(v.x); tile[r][cc + 1] = f2bf(v.y);
        tile[r][cc + 2] = f2bf(v.z); tile[r][cc + 3] = f2bf(v.w);
    }
    __syncthreads();
#pragma unroll
    for (int i = 0; i < 4; i++) {
        int idx = t + i * 256;
        int nn = idx >> 4, kc = (idx & 15) * 4;
        ushort4 v;
        v.x = tile[kc + 0][nn]; v.y = tile[kc + 1][nn];
        v.z = tile[kc + 2][nn]; v.w = tile[kc + 3][nn];
        *(ushort4*)&out[(size_t)(n0 + nn) * n + k0 + kc] = v;
    }
}

// ---------------- bf16 transpose: out[n][k] = in[k][n], n = 4096 ----------------
__global__ __launch_bounds__(256) void transpose_bf16_kernel(const unsigned short* __restrict__ in,
                                                             unsigned short* __restrict__ out, int n) {
    __shared__ unsigned short tile[64][65];
    int t = threadIdx.x;
    int n0 = blockIdx.x * 64, k0 = blockIdx.y * 64;
#pragma unroll
    for (int i = 0; i < 4; i++) {
        int idx = t + i * 256;
        int r = idx >> 4, cc = (idx & 15) * 4;
        ushort4 v = *(const ushort4*)&in[(size_t)(k0 + r) * n + n0 + cc];
        tile[r][cc + 0] = v.x; tile[r][cc + 1] = v.y;
        tile[r][cc + 2] = v.z; tile[r][cc + 3] = v.w;
    }
    __syncthreads();
#pragma unroll
    for (int i = 0; i < 4; i++) {
        int idx = t + i * 256;
        int nn = idx >> 4, kc = (idx & 15) * 4;
        ushort4 v;
        v.x = tile[kc + 0][nn]; v.y = tile[kc + 1][nn];
        v.z = tile[kc + 2][nn]; v.w = tile[kc + 3][nn];
        *(ushort4*)&out[(size_t)(n0 + nn) * n + k0 + kc] = v;
    }
}

// ---------------- GEMM: C[m,n] = sum_k A[m,k]*BT[n,k] + bias[n] (+ resid) ----------------
// MODE 0: write bf16 C, no residual. MODE 1: write fp32 C, add bf16 residual.
template <int MODE>
__global__ __launch_bounds__(256) void gemm_bt_kernel(
    const bf16* __restrict__ A, const bf16* __restrict__ BT,
    const float* __restrict__ bias, const bf16* __restrict__ resid,
    void* __restrict__ Cout, int M, int N, int K) {
    __shared__ __align__(16) bf16 As[128 * 32];
    __shared__ __align__(16) bf16 Bs[128 * 32];
    const int tid = threadIdx.x;
    const int wave = tid >> 6, lane = tid & 63;
    const int row0 = blockIdx.x * 128, col0 = blockIdx.y * 128;
    const int wr = wave >> 1, wc = wave & 1;
    const int lq = lane >> 4, lm = lane & 15;

    f32x4 acc[4][4];
#pragma unroll
    for (int mt = 0; mt < 4; mt++)
#pragma unroll
        for (int nt = 0; nt < 4; nt++) acc[mt][nt] = (f32x4){0.f, 0.f, 0.f, 0.f};

    const bf16* Ab = A + (size_t)row0 * K;
    const bf16* Bb = BT + (size_t)col0 * K;

    for (int k0 = 0; k0 < K; k0 += 32) {
#pragma unroll
        for (int i = 0; i < 2; i++) {
            int t = wave * 2 + i;
            int c = t * 64 + lane;
            int r = c >> 2, kc = c & 3;
            gld_lds16(Ab + (size_t)r * K + k0 + kc * 8, &As[t * 512]);
            gld_lds16(Bb + (size_t)r * K + k0 + kc * 8, &Bs[t * 512]);
        }
        __syncthreads();
        bf16x8 af[4], bfr[4];
#pragma unroll
        for (int mt = 0; mt < 4; mt++) {
            int r = wr * 64 + mt * 16 + lm;
            af[mt] = *(const bf16x8*)&As[r * 32 + lq * 8];
        }
#pragma unroll
        for (int nt = 0; nt < 4; nt++) {
            int r = wc * 64 + nt * 16 + lm;
            bfr[nt] = *(const bf16x8*)&Bs[r * 32 + lq * 8];
        }
#pragma unroll
        for (int mt = 0; mt < 4; mt++)
#pragma unroll
            for (int nt = 0; nt < 4; nt++)
                acc[mt][nt] = __builtin_amdgcn_mfma_f32_16x16x32_bf16(af[mt], bfr[nt], acc[mt][nt], 0, 0, 0);
        __syncthreads();
    }

    // C/D layout: col = lane&15, row = (lane>>4)*4 + reg
#pragma unroll
    for (int nt = 0; nt < 4; nt++) {
        int col = col0 + wc * 64 + nt * 16 + lm;
        float bv = bias[col];
#pragma unroll
        for (int mt = 0; mt < 4; mt++) {
            int rbase = row0 + wr * 64 + mt * 16 + lq * 4;
#pragma unroll
            for (int r = 0; r < 4; r++) {
                int row = rbase + r;
                float v = acc[mt][nt][r] + bv;
                if (MODE == 0) {
                    ((bf16*)Cout)[(size_t)row * N + col] = (bf16)v;
                } else {
                    v += (float)resid[(size_t)row * N + col];
                    ((float*)Cout)[(size_t)row * N + col] = v;
                }
            }
        }
    }
}

// ---------------- MFMA block-diagonal flash attention + residual ----------------
// grid: (nseg*8, 18). block = (seg, head, 64-row i-tile), 4 waves, 16 Q-rows/wave.
// Q in register A-frags; K tile row-major LDS; V^T tile (pre-transposed global) LDS.
__global__ __launch_bounds__(256, 2) void attn_kernel(
    const bf16* __restrict__ Q, const bf16* __restrict__ K, const bf16* __restrict__ Vt,
    const int* __restrict__ num_rels, const float* __restrict__ X,
    bf16* __restrict__ R1) {
    const float SCALE = 0.044194173824159216f;  // 1/sqrt(512)
    int seg = blockIdx.x >> 3;
    int h = blockIdx.x & 7;
    int S = 0;
    for (int i = 0; i < seg; i++) S += num_rels[i];
    int L = num_rels[seg];
    int i0 = blockIdx.y * 64;
    if (i0 >= L) return;

    __shared__ __align__(16) bf16 Ks[32][520];    // K tile, +8 pad -> conflict-free frags
    __shared__ __align__(16) bf16 Vs[512][40];    // V^T tile, +8 pad
    __shared__ __align__(16) bf16 Ps[4][16][40];  // per-wave P tile (C-layout -> A-layout)

    const int t = threadIdx.x;
    const int wave = t >> 6, lane = t & 63;
    const int lq = lane >> 4, lm = lane & 15;

    // Q rows for this wave, held as 16 A-fragments (row = lm, k-chunk c)
    const int qrow = i0 + wave * 16 + lm;
    const bool qvalid = qrow < L;
    bf16x8 aq[16];
    {
        const bf16* qb = Q + (size_t)(S + qrow) * 4096 + h * 512 + lq * 8;
#pragma unroll
        for (int c = 0; c < 16; c++) {
            bf16x8 v = {};
            if (qvalid) v = *(const bf16x8*)(qb + c * 32);
            aq[c] = v;
        }
    }

    f32x4 accO[32];
#pragma unroll
    for (int i = 0; i < 32; i++) accO[i] = (f32x4){0.f, 0.f, 0.f, 0.f};
    float m_r[4], l_r[4];
#pragma unroll
    for (int r = 0; r < 4; r++) { m_r[r] = -1e30f; l_r[r] = 0.f; }

    for (int j0 = 0; j0 < L; j0 += 32) {
        // stage K tile [32][512] (coalesced; rows past L hold neighboring data -> masked later)
#pragma unroll
        for (int it = 0; it < 8; it++) {
            int c = t + it * 256;
            int r = c >> 6, cc = (c & 63) * 8;
            *(uint4*)&Ks[r][cc] = *(const uint4*)&K[(size_t)(S + j0 + r) * 4096 + h * 512 + cc];
        }
        // stage V^T tile [512][32]
#pragma unroll
        for (int it = 0; it < 8; it++) {
            int c = t + it * 256;
            int r = c >> 2, cc = (c & 3) * 8;
            *(uint4*)&Vs[r][cc] = *(const uint4*)&Vt[(size_t)(h * 512 + r) * 4096 + S + j0 + cc];
        }
        __syncthreads();

        // S = Q K^T : 2 col-subtiles x 16 k-chunks
        f32x4 accS[2];
        accS[0] = (f32x4){0.f, 0.f, 0.f, 0.f};
        accS[1] = (f32x4){0.f, 0.f, 0.f, 0.f};
#pragma unroll
        for (int ct = 0; ct < 2; ct++)
#pragma unroll
            for (int c = 0; c < 16; c++) {
                bf16x8 bk = *(const bf16x8*)&Ks[ct * 16 + lm][c * 32 + lq * 8];
                accS[ct] = __builtin_amdgcn_mfma_f32_16x16x32_bf16(aq[c], bk, accS[ct], 0, 0, 0);
            }

        // online softmax; row i = lq*4 + r (C-layout), col j = j0 + ct*16 + lm
        bool v0 = (j0 + lm) < L, v1 = (j0 + 16 + lm) < L;
        float p0v[4], p1v[4], alpha[4];
#pragma unroll
        for (int r = 0; r < 4; r++) {
            float s0 = v0 ? accS[0][r] * SCALE : -1e30f;
            float s1 = v1 ? accS[1][r] * SCALE : -1e30f;
            float mx = fmaxf(s0, s1);
#pragma unroll
            for (int o = 1; o < 16; o <<= 1) mx = fmaxf(mx, __shfl_xor(mx, o, 64));
            float mnew = fmaxf(m_r[r], mx);
            alpha[r] = __expf(m_r[r] - mnew);
            float p0 = __expf(s0 - mnew), p1 = __expf(s1 - mnew);
            float sum = p0 + p1;
#pragma unroll
            for (int o = 1; o < 16; o <<= 1) sum += __shfl_xor(sum, o, 64);
            l_r[r] = l_r[r] * alpha[r] + sum;
            m_r[r] = mnew;
            p0v[r] = p0; p1v[r] = p1;
        }
        // write P to per-wave LDS tile (C-layout -> A-layout round trip)
#pragma unroll
        for (int r = 0; r < 4; r++) {
            Ps[wave][lq * 4 + r][lm] = (bf16)p0v[r];
            Ps[wave][lq * 4 + r][16 + lm] = (bf16)p1v[r];
        }
        // rescale O
#pragma unroll
        for (int i = 0; i < 32; i++)
#pragma unroll
            for (int r = 0; r < 4; r++) accO[i][r] *= alpha[r];

        // O += P V : A-frag from Ps (same wave; in-order LDS), B-frags from V^T tile
        bf16x8 ap = *(const bf16x8*)&Ps[wave][lm][lq * 8];
#pragma unroll
        for (int ct2 = 0; ct2 < 32; ct2++) {
            bf16x8 bv = *(const bf16x8*)&Vs[ct2 * 16 + lm][lq * 8];
            accO[ct2] = __builtin_amdgcn_mfma_f32_16x16x32_bf16(ap, bv, accO[ct2], 0, 0, 0);
        }
        __syncthreads();
    }

    // epilogue: row = i0 + wave*16 + lq*4 + r, col = ct2*16 + lm
#pragma unroll
    for (int r = 0; r < 4; r++) {
        int row = i0 + wave * 16 + lq * 4 + r;
        if (row >= L) continue;
        float inv = 1.f / l_r[r];
        size_t base = (size_t)(S + row) * 4096 + h * 512;
#pragma unroll
        for (int ct2 = 0; ct2 < 32; ct2++) {
            int col = ct2 * 16 + lm;
            R1[base + col] = (bf16)(accO[ct2][r] * inv + X[base + col]);
        }
    }
}

extern "C" void kernel_launch(void* const* d_in, const int* in_sizes, int n_in,
                              void* d_out, int out_size, void* d_ws, size_t ws_size,
                              hipStream_t stream) {
    const float* prod = (const float*)d_in[0];
    const int* nr = (const int*)d_in[1];
    const float* Wq = (const float*)d_in[2];
    const float* bq = (const float*)d_in[3];
    const float* Wk = (const float*)d_in[4];
    const float* bk = (const float*)d_in[5];
    const float* Wv = (const float*)d_in[6];
    const float* bv = (const float*)d_in[7];
    const float* Wfc = (const float*)d_in[8];
    const float* bfc = (const float*)d_in[9];
    float* out = (float*)d_out;

    const size_t MATB = (size_t)4096 * 4096 * sizeof(bf16);  // 33.55 MB
    char* ws = (char*)d_ws;
    bf16* Xb = (bf16*)(ws + 0 * MATB);   // bf16 prod_rep; later reused as V^T
    bf16* Qb = (bf16*)(ws + 1 * MATB);   // later reused as res1
    bf16* Kb = (bf16*)(ws + 2 * MATB);
    bf16* Vb = (bf16*)(ws + 3 * MATB);
    bf16* WT = (bf16*)(ws + 4 * MATB);   // reused per weight transpose

    int nseg = in_sizes[1];

    dim3 cb(256), cg(16384);
    dim3 tb(256), tg(64, 64);
    dim3 gb(256), gg(32, 32);

    cvt_kernel<<<cg, cb, 0, stream>>>(prod, Xb);

    cvt_transpose_kernel<<<tg, tb, 0, stream>>>(Wq, (unsigned short*)WT, 4096);
    gemm_bt_kernel<0><<<gg, gb, 0, stream>>>(Xb, WT, bq, nullptr, Qb, 4096, 4096, 4096);
    cvt_transpose_kernel<<<tg, tb, 0, stream>>>(Wk, (unsigned short*)WT, 4096);
    gemm_bt_kernel<0><<<gg, gb, 0, stream>>>(Xb, WT, bk, nullptr, Kb, 4096, 4096, 4096);
    cvt_transpose_kernel<<<tg, tb, 0, stream>>>(Wv, (unsigned short*)WT, 4096);
    gemm_bt_kernel<0><<<gg, gb, 0, stream>>>(Xb, WT, bv, nullptr, Vb, 4096, 4096, 4096);

    // V^T into the freed Xb slot
    transpose_bf16_kernel<<<tg, tb, 0, stream>>>((const unsigned short*)Vb, (unsigned short*)Xb, 4096);

    dim3 ab(256), ag(nseg * 8, 18);  // 18 * 64 >= Lmax = 1120
    attn_kernel<<<ag, ab, 0, stream>>>(Qb, Kb, Xb, nr, prod, Qb);

    cvt_transpose_kernel<<<tg, tb, 0, stream>>>(Wfc, (unsigned short*)WT, 4096);
    gemm_bt_kernel<1><<<gg, gb, 0, stream>>>(Qb, WT, bfc, Qb, out, 4096, 4096, 4096);
}